// Round 1
// baseline (6452.339 us; speedup 1.0000x reference)
//
#include <hip/hip_runtime.h>
#include <math.h>

#define N_V 5000
#define N_F 10000
#define C 128
#define NNZ 480000
#define LAYERS 30
#define SROWS 128

__device__ __forceinline__ float eluf(float x){ return x > 0.f ? x : expm1f(x); }

// v[n][c] = sum_k in[n][k] * W[k][c] + b[c]   (no BN on conv1)
__global__ void conv1_kernel(const float* __restrict__ in, const float* __restrict__ W,
                             const float* __restrict__ b, float* __restrict__ v){
    int t = blockIdx.x * blockDim.x + threadIdx.x;
    if(t >= N_V*C) return;
    int n = t >> 7, c = t & 127;
    float acc = b[c];
    acc += in[n*3+0]*W[0*C+c];
    acc += in[n*3+1]*W[1*C+c];
    acc += in[n*3+2]*W[2*C+c];
    v[t] = acc;
}

// y[rows[e]*32+j] += vals[e] * elu(x[cols[e]*32+j])
// reshape note: (B,N,128)->(4BN,32) is identity on the flat buffer.
__global__ void spmm_atomic(const int* __restrict__ rows, const int* __restrict__ cols,
                            const float* __restrict__ vals, const float* __restrict__ x,
                            float* __restrict__ y){
    int t = blockIdx.x * blockDim.x + threadIdx.x;
    int e = t >> 5;
    if(e >= NNZ) return;
    int j = t & 31;
    float xv = x[cols[e]*32 + j];
    xv = xv > 0.f ? xv : expm1f(xv);
    atomicAdd(&y[rows[e]*32 + j], vals[e]*xv);
}

// per-channel sum/sumsq of concat([maybe-elu(A0), A1]) over M rows -> st[0:256], st[256:512]
__global__ void stats_concat(const float* __restrict__ A0, int elu0,
                             const float* __restrict__ A1,
                             float* __restrict__ st, int M){
    int c = threadIdx.x;               // 256 threads
    int r0 = blockIdx.x * SROWS;
    int r1 = r0 + SROWS; if(r1 > M) r1 = M;
    float s = 0.f, s2 = 0.f;
    if(c < 128){
        for(int r = r0; r < r1; ++r){
            float v = A0[r*C + c];
            if(elu0) v = v > 0.f ? v : expm1f(v);
            s += v; s2 += v*v;
        }
    } else {
        int cc = c - 128;
        for(int r = r0; r < r1; ++r){
            float v = A1[r*C + cc];
            s += v; s2 += v*v;
        }
    }
    atomicAdd(&st[c], s);
    atomicAdd(&st[256 + c], s2);
}

// odd layers: stats of elu(V) plus masked sum for the global-average channels
// layout: st[0:128]=sum, st[128:256]=sumsq, st[256:384]=masked sum, st[384]=mask sum
__global__ void stats_avg(const float* __restrict__ V, const float* __restrict__ mask,
                          float* __restrict__ st, int M){
    int c = threadIdx.x;               // 128 threads
    int r0 = blockIdx.x * SROWS;
    int r1 = r0 + SROWS; if(r1 > M) r1 = M;
    float s=0.f, s2=0.f, sm=0.f, mk=0.f;
    for(int r=r0;r<r1;++r){
        float v = V[r*C + c];
        v = v > 0.f ? v : expm1f(v);
        float m = mask[r];
        s += v; s2 += v*v; sm += v*m;
        if(c==0) mk += m;
    }
    atomicAdd(&st[c], s);
    atomicAdd(&st[128+c], s2);
    atomicAdd(&st[256+c], sm);
    if(c==0) atomicAdd(&st[384], mk);
}

// fold BN into weights: Wf[k][j] = a_k*W[k][j]; bf[j] += (be_k - mean_k*a_k)*W[k][j]
__global__ void fold_concat(const float* __restrict__ st, const float* __restrict__ g,
                            const float* __restrict__ be, const float* __restrict__ W,
                            float* __restrict__ Wf, float* __restrict__ bf, float invM){
    int k = blockIdx.x;   // 256
    int j = threadIdx.x;  // 128
    float mean = st[k]*invM;
    float var = fmaxf(st[256+k]*invM - mean*mean, 0.f);
    float a = g[k]*rsqrtf(var + 1e-5f);
    float cc = be[k] - mean*a;
    float w = W[k*C + j];
    Wf[k*C + j] = a*w;
    atomicAdd(&bf[j], cc*w);
}

// odd layers: k<128 normal fold; k>=128 are broadcast-avg channels with var==0
// -> normalized value == be[k] exactly -> pure bias contribution.
__global__ void fold_odd(const float* __restrict__ st, const float* __restrict__ g,
                         const float* __restrict__ be, const float* __restrict__ W,
                         float* __restrict__ Wf, float* __restrict__ bf, float invM){
    int k = blockIdx.x;   // 256
    int j = threadIdx.x;  // 128
    float w = W[k*C + j];
    if(k < 128){
        float mean = st[k]*invM;
        float var = fmaxf(st[128+k]*invM - mean*mean, 0.f);
        float a = g[k]*rsqrtf(var + 1e-5f);
        float cc = be[k] - mean*a;
        Wf[k*C + j] = a*w;
        atomicAdd(&bf[j], cc*w);
    } else {
        atomicAdd(&bf[j], be[k]*w);
    }
}

// out[M,128] = concat(elu?(A0), elu?(A1)) @ Wf[K,128] + bf + bl (+ resid)
// tile 32x64, block 256, 2x4 acc/thread
__global__ __launch_bounds__(256) void gemm_kernel(
    const float* __restrict__ A0, int elu0,
    const float* __restrict__ A1, int elu1,
    const float* __restrict__ Wf, int K,
    const float* __restrict__ bf, const float* __restrict__ bl,
    const float* __restrict__ resid, float* __restrict__ out, int M)
{
    __shared__ float As[16][34];   // [kk][row], padded
    __shared__ float Ws[16][64];
    int tid = threadIdx.x;
    int tx = tid & 15;   // cols n0 + tx*4 .. +3
    int ty = tid >> 4;   // rows ty*2, ty*2+1
    int m0 = blockIdx.x * 32;
    int n0 = blockIdx.y * 64;
    float acc[2][4] = {{0.f,0.f,0.f,0.f},{0.f,0.f,0.f,0.f}};
    int nchunk = K >> 4;
    int lk = tid & 15;
    int lr = (tid >> 4) * 2;
    for(int kc = 0; kc < nchunk; ++kc){
        int kb = kc * 16;
        {   // stage A (32 rows x 16 k), elu applied at staging
            int kg = kb + lk;
            const float* src = A0; int kk = kg; int de = elu0;
            if(kg >= 128){ src = A1; kk = kg - 128; de = elu1; }
            #pragma unroll
            for(int r = 0; r < 2; ++r){
                int row = m0 + lr + r;
                float vv = (row < M) ? src[row*C + kk] : 0.f;
                if(de) vv = vv > 0.f ? vv : expm1f(vv);
                As[lk][lr + r] = vv;
            }
        }
        {   // stage W (16 k x 64 n)
            #pragma unroll
            for(int i = 0; i < 4; ++i){
                int idx = tid + i*256;      // 0..1023
                int kk = idx >> 6, j = idx & 63;
                Ws[kk][j] = Wf[(kb+kk)*C + n0 + j];
            }
        }
        __syncthreads();
        #pragma unroll
        for(int kk = 0; kk < 16; ++kk){
            float a0 = As[kk][ty*2+0];
            float a1 = As[kk][ty*2+1];
            float w[4];
            #pragma unroll
            for(int c2=0;c2<4;++c2) w[c2] = Ws[kk][tx*4+c2];
            #pragma unroll
            for(int c2=0;c2<4;++c2){ acc[0][c2] += a0*w[c2]; acc[1][c2] += a1*w[c2]; }
        }
        __syncthreads();
    }
    #pragma unroll
    for(int r=0;r<2;++r){
        int row = m0 + ty*2 + r;
        if(row >= M) continue;
        #pragma unroll
        for(int c2=0;c2<4;++c2){
            int j = n0 + tx*4 + c2;
            float vv = acc[r][c2] + bf[j] + bl[j];
            if(resid) vv += resid[row*C + j];
            out[row*C + j] = vv;
        }
    }
}

// final conv2 fold: fscale[k]=a_k*Wout[k]; ff[128]=sum_k (be_k-mean_k*a_k)*Wout[k] + bout
__global__ void fold_final(const float* __restrict__ st, const float* __restrict__ g,
                           const float* __restrict__ be, const float* __restrict__ Wo,
                           const float* __restrict__ bo, float* __restrict__ ff, float invM){
    int k = threadIdx.x; // 128
    float mean = st[k]*invM;
    float var = fmaxf(st[256+k]*invM - mean*mean, 0.f);
    float a = g[k]*rsqrtf(var+1e-5f);
    float w = Wo[k];
    ff[k] = a*w;
    __shared__ float red[128];
    red[k] = (be[k]-mean*a)*w;
    __syncthreads();
    for(int s=64;s>0;s>>=1){ if(k<s) red[k]+=red[k+s]; __syncthreads(); }
    if(k==0) ff[128] = red[0] + bo[0];
}

__global__ void final_out(const float* __restrict__ V, const float* __restrict__ ff,
                          float* __restrict__ out){
    int n = blockIdx.x;
    int k = threadIdx.x; // 128
    float p = V[n*C+k]*ff[k];
    __shared__ float red[128];
    red[k]=p; __syncthreads();
    for(int s=64;s>0;s>>=1){ if(k<s) red[k]+=red[k+s]; __syncthreads(); }
    if(k==0){ float v = red[0] + ff[128]; out[n] = v>0.f? v: expm1f(v); }
}

extern "C" void kernel_launch(void* const* d_in, const int* in_sizes, int n_in,
                              void* d_out, int out_size, void* d_ws, size_t ws_size,
                              hipStream_t stream){
    const float* inputs  = (const float*)d_in[0];
    const float* mask    = (const float*)d_in[1];
    const int*   Di_rows = (const int*)d_in[2];
    const int*   Di_cols = (const int*)d_in[3];
    const float* Di_vals = (const float*)d_in[4];
    const int*   DiA_rows= (const int*)d_in[5];
    const int*   DiA_cols= (const int*)d_in[6];
    const float* DiA_vals= (const float*)d_in[7];
    const float* W_in = (const float*)d_in[8];
    const float* b_in = (const float*)d_in[9];
    const float* g0  = (const float*)d_in[10];
    const float* be0 = (const float*)d_in[11];
    const float* W0  = (const float*)d_in[12];
    const float* b0  = (const float*)d_in[13];
    const float* g1  = (const float*)d_in[14];
    const float* be1 = (const float*)d_in[15];
    const float* Wl1 = (const float*)d_in[16];
    const float* bl1 = (const float*)d_in[17];
    const float* g2  = (const float*)d_in[18];
    const float* be2 = (const float*)d_in[19];
    const float* W_out = (const float*)d_in[20];
    const float* b_out = (const float*)d_in[21];

    float* ws = (float*)d_ws;
    float* v    = ws;                    // 640000
    float* vb   = ws + 640000;           // 640000
    float* f    = ws + 1280000;          // 1280000
    float* fb   = ws + 2560000;          // 1280000
    float* Dv   = ws + 3840000;          // 1280000 (x1 aliases first 640000 on odd layers)
    float* DAf  = ws + 5120000;          // 640000
    float* x1   = Dv;                    // alias: Dv unused on odd layers
    float* Wf   = ws + 5760000;          // 32768
    float* stats= ws + 5792768;          // 61*512 = 31232
    float* bias = ws + 5824000;          // 61*128 = 7808
    float* ff   = ws + 5831808;          // 132
    // total ~5.83M floats ~= 23.3 MB

    // zero all stats+bias slots in one shot; zero f (face features start at 0)
    hipMemsetAsync(stats, 0, (31232 + 7808)*sizeof(float), stream);
    hipMemsetAsync(f, 0, (size_t)1280000*sizeof(float), stream);
    conv1_kernel<<<2500, 256, 0, stream>>>(inputs, W_in, b_in, v);

    int slot = 0;
    for(int i=0;i<LAYERS;++i){
        if((i & 1) == 0){
            // DirResNet2
            hipMemsetAsync(Dv, 0, (size_t)(1280000+640000)*sizeof(float), stream); // Dv + DAf
            spmm_atomic<<<60000, 256, 0, stream>>>(Di_rows, Di_cols, Di_vals, v, Dv);
            float* st = stats + slot*512; float* bslot = bias + slot*128; ++slot;
            stats_concat<<<(N_F+SROWS-1)/SROWS, 256, 0, stream>>>(f, 1, Dv, st, N_F);
            fold_concat<<<256, 128, 0, stream>>>(st, g0+i*256, be0+i*256, W0+(size_t)i*32768, Wf, bslot, 1.f/N_F);
            dim3 gf((N_F+31)/32, 2);
            gemm_kernel<<<gf, 256, 0, stream>>>(f, 1, Dv, 0, Wf, 256, bslot, b0+i*128, nullptr, fb, N_F);
            spmm_atomic<<<60000, 256, 0, stream>>>(DiA_rows, DiA_cols, DiA_vals, fb, DAf);
            st = stats + slot*512; bslot = bias + slot*128; ++slot;
            stats_concat<<<(N_V+SROWS-1)/SROWS, 256, 0, stream>>>(v, 1, DAf, st, N_V);
            fold_concat<<<256, 128, 0, stream>>>(st, g1+i*256, be1+i*256, Wl1+(size_t)i*32768, Wf, bslot, 1.f/N_V);
            dim3 gv((N_V+31)/32, 2);
            gemm_kernel<<<gv, 256, 0, stream>>>(v, 1, DAf, 0, Wf, 256, bslot, bl1+i*128, v, vb, N_V);
            { float* t=v; v=vb; vb=t; }
            { float* t=f; f=fb; fb=t; }
        } else {
            // AvgResNet2
            dim3 gv((N_V+31)/32, 2);
            float* st = stats + slot*512; float* bslot = bias + slot*128; ++slot;
            stats_avg<<<(N_V+SROWS-1)/SROWS, 128, 0, stream>>>(v, mask, st, N_V);
            fold_odd<<<256, 128, 0, stream>>>(st, g0+i*256, be0+i*256, W0+(size_t)i*32768, Wf, bslot, 1.f/N_V);
            gemm_kernel<<<gv, 256, 0, stream>>>(v, 1, nullptr, 0, Wf, 128, bslot, b0+i*128, nullptr, x1, N_V);
            st = stats + slot*512; bslot = bias + slot*128; ++slot;
            stats_avg<<<(N_V+SROWS-1)/SROWS, 128, 0, stream>>>(x1, mask, st, N_V);
            fold_odd<<<256, 128, 0, stream>>>(st, g1+i*256, be1+i*256, Wl1+(size_t)i*32768, Wf, bslot, 1.f/N_V);
            gemm_kernel<<<gv, 256, 0, stream>>>(x1, 1, nullptr, 0, Wf, 128, bslot, bl1+i*128, v, vb, N_V);
            { float* t=v; v=vb; vb=t; }
        }
    }
    // conv2: BN over raw v, then @ W_out (128->1), elu
    float* st = stats + slot*512; ++slot;
    stats_concat<<<(N_V+SROWS-1)/SROWS, 256, 0, stream>>>(v, 0, v, st, N_V);
    fold_final<<<1, 128, 0, stream>>>(st, g2, be2, W_out, b_out, ff, 1.f/N_V);
    final_out<<<5000, 128, 0, stream>>>(v, ff, (float*)d_out);
}

// Round 2
// 4927.968 us; speedup vs baseline: 1.3093x; 1.3093x over previous
//
#include <hip/hip_runtime.h>
#include <math.h>

#define N_V 5000
#define N_F 10000
#define C 128
#define NNZ 480000
#define LAYERS 30
#define SROWS 64

__device__ __forceinline__ float eluf(float x){ return x > 0.f ? x : expm1f(x); }

// conv1: v[n][c] = in[n][:3] @ W + b ; also write elu(v)
__global__ void conv1_kernel(const float* __restrict__ in, const float* __restrict__ W,
                             const float* __restrict__ b, float* __restrict__ v,
                             float* __restrict__ ev){
    int t = blockIdx.x * blockDim.x + threadIdx.x;
    if(t >= N_V*C) return;
    int n = t >> 7, c = t & 127;
    float acc = b[c];
    acc += in[n*3+0]*W[0*C+c];
    acc += in[n*3+1]*W[1*C+c];
    acc += in[n*3+2]*W[2*C+c];
    v[t] = acc;
    ev[t] = eluf(acc);
}

// ---------------- CSR build (per call; indices are inputs) ----------------
__global__ void hist_kernel(const int* __restrict__ rows, int* __restrict__ hist, int nnz){
    int e = blockIdx.x*256 + threadIdx.x;
    if(e < nnz) atomicAdd(&hist[rows[e]], 1);
}

__global__ void scan_block(const int* __restrict__ in, int* __restrict__ out,
                           int* __restrict__ bsum, int n){
    __shared__ int sh[256];
    int tid = threadIdx.x; int i = blockIdx.x*256 + tid;
    int v = (i < n) ? in[i] : 0;
    sh[tid] = v; __syncthreads();
    for(int off = 1; off < 256; off <<= 1){
        int t = (tid >= off) ? sh[tid-off] : 0;
        __syncthreads();
        sh[tid] += t;
        __syncthreads();
    }
    if(i < n) out[i] = sh[tid] - v;           // exclusive
    if(tid == 255) bsum[blockIdx.x] = sh[255];
}

__global__ void scan_top(int* __restrict__ bsum, int nb){
    __shared__ int sh[256];
    int tid = threadIdx.x;
    int v = (tid < nb) ? bsum[tid] : 0;
    sh[tid] = v; __syncthreads();
    for(int off = 1; off < 256; off <<= 1){
        int t = (tid >= off) ? sh[tid-off] : 0;
        __syncthreads();
        sh[tid] += t;
        __syncthreads();
    }
    if(tid < nb) bsum[tid] = sh[tid] - v;     // exclusive
}

__global__ void scan_add(int* __restrict__ ptr, int* __restrict__ cur,
                         const int* __restrict__ bsum, int n, int total){
    int i = blockIdx.x*256 + threadIdx.x;
    if(i < n){ int v = ptr[i] + bsum[blockIdx.x]; ptr[i] = v; cur[i] = v; }
    if(i == 0) ptr[n] = total;
}

__global__ void scatter_perm(const int* __restrict__ rows, int* __restrict__ cur,
                             int* __restrict__ perm, int nnz){
    int e = blockIdx.x*256 + threadIdx.x;
    if(e >= nnz) return;
    int pos = atomicAdd(&cur[rows[e]], 1);
    perm[pos] = e;
}

// ---------------- SpMM as CSR gather: y[row][j] = sum_e vals[e]*x[cols[e]][j] ----
// x is already elu'd by its producer. Writes every row (incl. empty -> 0).
__global__ void spmm_gather(const int* __restrict__ ptr, const int* __restrict__ perm,
                            const int* __restrict__ cols, const float* __restrict__ vals,
                            const float* __restrict__ x, float* __restrict__ y, int nrows){
    int row = blockIdx.x*8 + (threadIdx.x >> 5);
    int j = threadIdx.x & 31;
    if(row >= nrows) return;
    int s = ptr[row], e = ptr[row+1];
    float acc = 0.f;
    for(int i = s; i < e; ++i){
        int ee = perm[i];
        acc += vals[ee] * x[cols[ee]*32 + j];
    }
    y[row*32 + j] = acc;
}

// ---------------- BN stats ----------------
// concat stats: A0 (pre-elu'd, 128ch) -> st[0:128]; A1 (raw spmm out, viewed (M,128)) -> st[128:256];
// sumsq at st[256+...]
__global__ void stats_concat(const float* __restrict__ A0, const float* __restrict__ A1,
                             float* __restrict__ st, int M){
    int c = threadIdx.x;               // 256 threads
    int r0 = blockIdx.x * SROWS;
    int r1 = r0 + SROWS; if(r1 > M) r1 = M;
    float s = 0.f, s2 = 0.f;
    if(c < 128){
        for(int r = r0; r < r1; ++r){ float v = A0[r*C + c]; s += v; s2 += v*v; }
    } else {
        int cc = c - 128;
        for(int r = r0; r < r1; ++r){ float v = A1[r*C + cc]; s += v; s2 += v*v; }
    }
    atomicAdd(&st[c], s);
    atomicAdd(&st[256 + c], s2);
}

// single-source stats (128 ch): sums -> st[0:128], sumsq -> st[256:384]
__global__ void stats_single(const float* __restrict__ A, float* __restrict__ st, int M){
    int c = threadIdx.x;               // 128 threads
    int r0 = blockIdx.x * SROWS;
    int r1 = r0 + SROWS; if(r1 > M) r1 = M;
    float s = 0.f, s2 = 0.f;
    for(int r = r0; r < r1; ++r){ float v = A[r*C + c]; s += v; s2 += v*v; }
    atomicAdd(&st[c], s);
    atomicAdd(&st[256 + c], s2);
}

// ---------------- BN fold into weights ----------------
__global__ void fold_concat(const float* __restrict__ st, const float* __restrict__ g,
                            const float* __restrict__ be, const float* __restrict__ W,
                            float* __restrict__ Wf, float* __restrict__ bf, float invM){
    int k = blockIdx.x;   // 256
    int j = threadIdx.x;  // 128
    float mean = st[k]*invM;
    float var = fmaxf(st[256+k]*invM - mean*mean, 0.f);
    float a = g[k]*rsqrtf(var + 1e-5f);
    float cc = be[k] - mean*a;
    float w = W[k*C + j];
    Wf[k*C + j] = a*w;
    atomicAdd(&bf[j], cc*w);
}

// odd layers: k<128 normal fold; k>=128 are broadcast-avg channels (var==0 analytically)
// -> normalized value == be[k] exactly -> pure bias contribution; K shrinks to 128.
__global__ void fold_odd(const float* __restrict__ st, const float* __restrict__ g,
                         const float* __restrict__ be, const float* __restrict__ W,
                         float* __restrict__ Wf, float* __restrict__ bf, float invM){
    int k = blockIdx.x;   // 256
    int j = threadIdx.x;  // 128
    float w = W[k*C + j];
    if(k < 128){
        float mean = st[k]*invM;
        float var = fmaxf(st[256+k]*invM - mean*mean, 0.f);
        float a = g[k]*rsqrtf(var + 1e-5f);
        float cc = be[k] - mean*a;
        Wf[k*C + j] = a*w;
        atomicAdd(&bf[j], cc*w);
    } else {
        atomicAdd(&bf[j], be[k]*w);
    }
}

// ---------------- GEMM: out[M,128] = concat(A0,A1) @ Wf[K,128] + bf + bl (+resid) ----
// 32x128 tile per block (all cols in one block -> in-place raw/elu writes are safe:
// all A staging reads of this block's rows happen before the last __syncthreads).
__global__ __launch_bounds__(256) void gemm_kernel(
    const float* __restrict__ A0, const float* __restrict__ A1,
    const float* __restrict__ Wf, int K,
    const float* __restrict__ bf, const float* __restrict__ bl,
    const float* __restrict__ resid, float* __restrict__ out_raw,
    float* __restrict__ out_elu, int M)
{
    __shared__ float As[16][33];
    __shared__ float Ws[16][128];
    int tid = threadIdx.x;
    int tx = tid & 15;    // 8 cols each: j = tx*8..tx*8+7
    int ty = tid >> 4;    // 2 rows each
    int m0 = blockIdx.x * 32;
    float acc[2][8] = {};
    int lk = tid & 15;
    int lr = (tid >> 4) * 2;
    int nch = K >> 4;
    for(int kc = 0; kc < nch; ++kc){
        int kb = kc * 16;
        {   // stage A (32 rows x 16 k)
            int kg = kb + lk;
            const float* src = A0; int kk = kg;
            if(kg >= 128){ src = A1; kk = kg - 128; }
            #pragma unroll
            for(int r = 0; r < 2; ++r){
                int row = m0 + lr + r;
                As[lk][lr + r] = (row < M) ? src[row*C + kk] : 0.f;
            }
        }
        {   // stage W (16 k x 128 n)
            #pragma unroll
            for(int i2 = 0; i2 < 8; ++i2){
                int idx = tid + i2*256;
                int kk2 = idx >> 7, j = idx & 127;
                Ws[kk2][j] = Wf[(kb+kk2)*C + j];
            }
        }
        __syncthreads();
        #pragma unroll
        for(int kk2 = 0; kk2 < 16; ++kk2){
            float a0 = As[kk2][ty*2];
            float a1 = As[kk2][ty*2+1];
            const float4 w0 = *(const float4*)&Ws[kk2][tx*8];
            const float4 w1 = *(const float4*)&Ws[kk2][tx*8+4];
            float w[8] = {w0.x,w0.y,w0.z,w0.w,w1.x,w1.y,w1.z,w1.w};
            #pragma unroll
            for(int c2 = 0; c2 < 8; ++c2){ acc[0][c2] += a0*w[c2]; acc[1][c2] += a1*w[c2]; }
        }
        __syncthreads();
    }
    #pragma unroll
    for(int r = 0; r < 2; ++r){
        int row = m0 + ty*2 + r;
        if(row >= M) continue;
        #pragma unroll
        for(int c2 = 0; c2 < 8; ++c2){
            int j = tx*8 + c2;
            float vv = acc[r][c2] + bf[j] + bl[j];
            if(resid) vv += resid[row*C + j];
            if(out_raw) out_raw[row*C + j] = vv;
            if(out_elu) out_elu[row*C + j] = eluf(vv);
        }
    }
}

// ---------------- final conv2 ----------------
__global__ void fold_final(const float* __restrict__ st, const float* __restrict__ g,
                           const float* __restrict__ be, const float* __restrict__ Wo,
                           const float* __restrict__ bo, float* __restrict__ ff, float invM){
    int k = threadIdx.x; // 128
    float mean = st[k]*invM;
    float var = fmaxf(st[256+k]*invM - mean*mean, 0.f);
    float a = g[k]*rsqrtf(var+1e-5f);
    float w = Wo[k];
    ff[k] = a*w;
    __shared__ float red[128];
    red[k] = (be[k]-mean*a)*w;
    __syncthreads();
    for(int s=64;s>0;s>>=1){ if(k<s) red[k]+=red[k+s]; __syncthreads(); }
    if(k==0) ff[128] = red[0] + bo[0];
}

__global__ void final_out(const float* __restrict__ V, const float* __restrict__ ff,
                          float* __restrict__ out){
    int n = blockIdx.x;
    int k = threadIdx.x; // 128
    float p = V[n*C+k]*ff[k];
    __shared__ float red[128];
    red[k]=p; __syncthreads();
    for(int s=64;s>0;s>>=1){ if(k<s) red[k]+=red[k+s]; __syncthreads(); }
    if(k==0){ float v = red[0] + ff[128]; out[n] = v>0.f? v: expm1f(v); }
}

extern "C" void kernel_launch(void* const* d_in, const int* in_sizes, int n_in,
                              void* d_out, int out_size, void* d_ws, size_t ws_size,
                              hipStream_t stream){
    const float* inputs  = (const float*)d_in[0];
    const int*   Di_rows = (const int*)d_in[2];
    const int*   Di_cols = (const int*)d_in[3];
    const float* Di_vals = (const float*)d_in[4];
    const int*   DiA_rows= (const int*)d_in[5];
    const int*   DiA_cols= (const int*)d_in[6];
    const float* DiA_vals= (const float*)d_in[7];
    const float* W_in = (const float*)d_in[8];
    const float* b_in = (const float*)d_in[9];
    const float* g0  = (const float*)d_in[10];
    const float* be0 = (const float*)d_in[11];
    const float* W0  = (const float*)d_in[12];
    const float* b0  = (const float*)d_in[13];
    const float* g1  = (const float*)d_in[14];
    const float* be1 = (const float*)d_in[15];
    const float* Wl1 = (const float*)d_in[16];
    const float* bl1 = (const float*)d_in[17];
    const float* g2  = (const float*)d_in[18];
    const float* be2 = (const float*)d_in[19];
    const float* W_out = (const float*)d_in[20];
    const float* b_out = (const float*)d_in[21];

    float* ws = (float*)d_ws;
    float* v_raw = ws;                   // 640000
    float* elu_v = ws + 640000;          // 640000
    float* elu_f = ws + 1280000;         // 1280000
    float* Dv    = ws + 2560000;         // 1280000 (x1_elu aliases first 640000)
    float* DAf   = ws + 3840000;         // 640000
    float* x1    = Dv;
    float* Wf    = ws + 4480000;         // 32768
    float* stats = ws + 4512768;         // 61*512
    float* bias  = ws + 4544000;         // 61*128
    float* ff    = ws + 4551808;         // 132
    int* Di_ptr  = (int*)(ws + 4551940); // 40001
    int* Di_cur  = (int*)(ws + 4591941); // 40000
    int* Di_perm = (int*)(ws + 4631941); // 480000
    int* DA_ptr  = (int*)(ws + 5111941); // 20001
    int* DA_cur  = (int*)(ws + 5131942); // 20000
    int* DA_perm = (int*)(ws + 5151942); // 480000
    int* bsum    = (int*)(ws + 5631942); // 160
    // total ~5.63M floats ~= 22.5 MB

    // zero stats+bias+ff (contiguous) and elu_f (f starts at 0 -> elu(0)=0)
    hipMemsetAsync(stats, 0, (size_t)(31232 + 7808 + 132)*sizeof(float), stream);
    hipMemsetAsync(elu_f, 0, (size_t)1280000*sizeof(float), stream);

    // CSR build: Di (40000 rows), DiA (20000 rows)
    hipMemsetAsync(Di_cur, 0, (size_t)40000*sizeof(int), stream);
    hist_kernel<<<(NNZ+255)/256, 256, 0, stream>>>(Di_rows, Di_cur, NNZ);
    scan_block<<<(40000+255)/256, 256, 0, stream>>>(Di_cur, Di_ptr, bsum, 40000);
    scan_top<<<1, 256, 0, stream>>>(bsum, (40000+255)/256);
    scan_add<<<(40000+255)/256, 256, 0, stream>>>(Di_ptr, Di_cur, bsum, 40000, NNZ);
    scatter_perm<<<(NNZ+255)/256, 256, 0, stream>>>(Di_rows, Di_cur, Di_perm, NNZ);

    hipMemsetAsync(DA_cur, 0, (size_t)20000*sizeof(int), stream);
    hist_kernel<<<(NNZ+255)/256, 256, 0, stream>>>(DiA_rows, DA_cur, NNZ);
    scan_block<<<(20000+255)/256, 256, 0, stream>>>(DA_cur, DA_ptr, bsum, 20000);
    scan_top<<<1, 256, 0, stream>>>(bsum, (20000+255)/256);
    scan_add<<<(20000+255)/256, 256, 0, stream>>>(DA_ptr, DA_cur, bsum, 20000, NNZ);
    scatter_perm<<<(NNZ+255)/256, 256, 0, stream>>>(DiA_rows, DA_cur, DA_perm, NNZ);

    conv1_kernel<<<(N_V*C+255)/256, 256, 0, stream>>>(inputs, W_in, b_in, v_raw, elu_v);

    int slot = 0;
    for(int i = 0; i < LAYERS; ++i){
        if((i & 1) == 0){
            // DirResNet2
            spmm_gather<<<5000, 256, 0, stream>>>(Di_ptr, Di_perm, Di_cols, Di_vals,
                                                  elu_v, Dv, 40000);
            float* st = stats + slot*512; float* bs = bias + slot*128; ++slot;
            stats_concat<<<(N_F+SROWS-1)/SROWS, 256, 0, stream>>>(elu_f, Dv, st, N_F);
            fold_concat<<<256, 128, 0, stream>>>(st, g0+i*256, be0+i*256,
                                                 W0+(size_t)i*32768, Wf, bs, 1.f/N_F);
            gemm_kernel<<<(N_F+31)/32, 256, 0, stream>>>(elu_f, Dv, Wf, 256, bs, b0+i*128,
                                                         nullptr, nullptr, elu_f, N_F);
            spmm_gather<<<2500, 256, 0, stream>>>(DA_ptr, DA_perm, DiA_cols, DiA_vals,
                                                  elu_f, DAf, 20000);
            st = stats + slot*512; bs = bias + slot*128; ++slot;
            stats_concat<<<(N_V+SROWS-1)/SROWS, 256, 0, stream>>>(elu_v, DAf, st, N_V);
            fold_concat<<<256, 128, 0, stream>>>(st, g1+i*256, be1+i*256,
                                                 Wl1+(size_t)i*32768, Wf, bs, 1.f/N_V);
            gemm_kernel<<<(N_V+31)/32, 256, 0, stream>>>(elu_v, DAf, Wf, 256, bs, bl1+i*128,
                                                         v_raw, v_raw, elu_v, N_V);
        } else {
            // AvgResNet2 (avg/mask drop out analytically: broadcast ch var=0 -> beta)
            float* st = stats + slot*512; float* bs = bias + slot*128; ++slot;
            stats_single<<<(N_V+SROWS-1)/SROWS, 128, 0, stream>>>(elu_v, st, N_V);
            fold_odd<<<256, 128, 0, stream>>>(st, g0+i*256, be0+i*256,
                                              W0+(size_t)i*32768, Wf, bs, 1.f/N_V);
            gemm_kernel<<<(N_V+31)/32, 256, 0, stream>>>(elu_v, nullptr, Wf, 128, bs, b0+i*128,
                                                         nullptr, nullptr, x1, N_V);
            st = stats + slot*512; bs = bias + slot*128; ++slot;
            stats_single<<<(N_V+SROWS-1)/SROWS, 128, 0, stream>>>(x1, st, N_V);
            fold_odd<<<256, 128, 0, stream>>>(st, g1+i*256, be1+i*256,
                                              Wl1+(size_t)i*32768, Wf, bs, 1.f/N_V);
            gemm_kernel<<<(N_V+31)/32, 256, 0, stream>>>(x1, nullptr, Wf, 128, bs, bl1+i*128,
                                                         v_raw, v_raw, elu_v, N_V);
        }
    }
    // conv2: BN over raw v, @ W_out (128->1), elu
    float* st = stats + slot*512; ++slot;
    stats_single<<<(N_V+SROWS-1)/SROWS, 128, 0, stream>>>(v_raw, st, N_V);
    fold_final<<<1, 128, 0, stream>>>(st, g2, be2, W_out, b_out, ff, 1.f/N_V);
    final_out<<<5000, 128, 0, stream>>>(v_raw, ff, (float*)d_out);
}